// Round 1
// baseline (412.882 us; speedup 1.0000x reference)
//
#include <hip/hip_runtime.h>

#define DD 128
#define SCAN_CHUNK 2048   // 256 threads x 8 elements per scan block
#define NXCD 8            // MI355X: 8 XCDs, private L2 each

typedef __attribute__((ext_vector_type(8))) short bf16x8;
typedef __attribute__((ext_vector_type(4))) float f32x4;

__device__ __forceinline__ short f2bf(float f) {
    union { float f; unsigned u; } x; x.f = f;
    unsigned r = x.u + 0x7FFF + ((x.u >> 16) & 1);   // round-to-nearest-even
    return (short)(r >> 16);
}

// Physical XCD id (0..7). All waves of a workgroup run on one XCD; every
// memory op from XCD x is serviced by L2 x, so XCD-private data needs no
// cross-XCD coherence.
__device__ __forceinline__ int xcc_id() {
    int x;
    asm volatile("s_getreg_b32 %0, hwreg(HW_REG_XCC_ID)" : "=s"(x));
    return x & (NXCD - 1);
}

// Workgroup-scope atomic: emits global_atomic_add WITHOUT sc1 -> RMW executes
// in the local (XCD) L2 instead of the memory-side coherence point. Correct
// here because each counter copy is only ever touched by one XCD (hardware
// routing invariant), and copies are line-disjoint so no 64B line is dirty in
// two L2s. Dispatch-boundary L2 writeback makes results visible to the scan.
__device__ __forceinline__ int l2_atomic_inc(int* p) {
    return __hip_atomic_fetch_add(p, 1, __ATOMIC_RELAXED, __HIP_MEMORY_SCOPE_WORKGROUP);
}

// ---------------------------------------------------------------------------
// k_hist2: histogram both graphs into per-XCD private counters with XCD-local
// (L2) atomics; capture each element's (xcd, local-rank) packed as
// (x<<24)|rank. 8 elements per thread -> 8 independent atomic chains.
// ---------------------------------------------------------------------------
__global__ __launch_bounds__(256)
void k_hist2(const int* __restrict__ g1d, const int* __restrict__ g2d,
             int* __restrict__ cnt1x, int* __restrict__ cnt2x,
             int* __restrict__ rank1, int* __restrict__ rank2,
             int nnz, int no, int str1, int str2) {
    int gid = blockIdx.x * 256 + threadIdx.x;
    const int* dst; int* cnt; int* rank; int q; int str;
    if (gid < no) { dst = g1d; cnt = cnt1x; rank = rank1; str = str1; q = gid; }
    else {
        q = gid - no;
        if (q >= no) return;
        dst = g2d; cnt = cnt2x; rank = rank2; str = str2;
    }
    const int xc = xcc_id();
    int* mycnt = cnt + (size_t)xc * str;     // this XCD's private copy
    const int tag = xc << 24;

    int i = q << 3;
    if (i + 8 <= nnz) {
        int4 d0 = *(const int4*)(dst + i);
        int4 d1 = *(const int4*)(dst + i + 4);
        int r0 = l2_atomic_inc(&mycnt[d0.x]);
        int r1 = l2_atomic_inc(&mycnt[d0.y]);
        int r2 = l2_atomic_inc(&mycnt[d0.z]);
        int r3 = l2_atomic_inc(&mycnt[d0.w]);
        int r4 = l2_atomic_inc(&mycnt[d1.x]);
        int r5 = l2_atomic_inc(&mycnt[d1.y]);
        int r6 = l2_atomic_inc(&mycnt[d1.z]);
        int r7 = l2_atomic_inc(&mycnt[d1.w]);
        *(int4*)(rank + i)     = make_int4(tag | r0, tag | r1, tag | r2, tag | r3);
        *(int4*)(rank + i + 4) = make_int4(tag | r4, tag | r5, tag | r6, tag | r7);
    } else {
        for (; i < nnz; ++i) rank[i] = tag | l2_atomic_inc(&mycnt[dst[i]]);
    }
}

// ---------------------------------------------------------------------------
// k_scan_blocks2: per-bucket total = sum over the 8 XCD copies; then the usual
// chunked exclusive scan producing off[] and per-chunk sums.
// ---------------------------------------------------------------------------
__global__ __launch_bounds__(256)
void k_scan_blocks2(const int* __restrict__ cnt1, int* __restrict__ off1,
                    const int* __restrict__ cnt2, int* __restrict__ off2,
                    int* __restrict__ bsum, int n1, int n2, int nb1,
                    int str1, int str2) {
    __shared__ int sh[256];
    const int tid = threadIdx.x;
    const int b = blockIdx.x;
    const int* cnt; int* off; int* bs; int n; int lb; int str;
    if (b < nb1) { cnt = cnt1; off = off1; bs = bsum;      n = n1; lb = b;       str = str1; }
    else         { cnt = cnt2; off = off2; bs = bsum + 64; n = n2; lb = b - nb1; str = str2; }

    const int base = lb * SCAN_CHUNK + tid * 8;
    int v[8];
    int s = 0;
    #pragma unroll
    for (int j = 0; j < 8; ++j) {
        int idx = base + j;
        int t = 0;
        if (idx < n) {
            #pragma unroll
            for (int x = 0; x < NXCD; ++x) t += cnt[(size_t)x * str + idx];
        }
        v[j] = t;
        s += t;
    }
    sh[tid] = s;
    __syncthreads();
    for (int d = 1; d < 256; d <<= 1) {
        int y = (tid >= d) ? sh[tid - d] : 0;
        __syncthreads();
        sh[tid] += y;
        __syncthreads();
    }
    int incl = sh[tid];
    int run = incl - s;
    #pragma unroll
    for (int j = 0; j < 8; ++j) {
        int idx = base + j;
        if (idx < n) off[idx] = run;
        run += v[j];
    }
    if (tid == 255) bs[lb] = incl;
}

__global__ void k_scan_top2(int* __restrict__ bsum, int nb1, int nb2) {
    if (threadIdx.x == 0) {
        int run = 0;
        for (int i = 0; i < nb1; ++i) { int t = bsum[i]; bsum[i] = run; run += t; }
    } else if (threadIdx.x == 1) {
        int run = 0;
        for (int i = 0; i < nb2; ++i) { int t = bsum[64 + i]; bsum[64 + i] = run; run += t; }
    }
}

// ---------------------------------------------------------------------------
// k_scan_add2: finalize off[] with the top-level scan, AND materialize per-XCD
// bases: base[x][e] = off[e] + sum_{x'<x} cnt[x'][e]  (what k_fill2 indexes).
// ---------------------------------------------------------------------------
__global__ __launch_bounds__(256)
void k_scan_add2(int* __restrict__ off1, int* __restrict__ off2,
                 const int* __restrict__ bsum,
                 const int* __restrict__ cnt1x, int* __restrict__ base1,
                 const int* __restrict__ cnt2x, int* __restrict__ base2,
                 int n1, int n2, int str1, int str2, int nnz) {
    int gid = blockIdx.x * 256 + threadIdx.x;
    if (gid < n1) {
        int o = off1[gid] + bsum[gid >> 11];            // SCAN_CHUNK == 2048
        off1[gid] = o;
        #pragma unroll
        for (int x = 0; x < NXCD; ++x) {
            int c = cnt1x[(size_t)x * str1 + gid];
            base1[(size_t)x * str1 + gid] = o;
            o += c;
        }
    } else {
        int g = gid - n1;
        if (g < n2) {
            int o = off2[g] + bsum[64 + (g >> 11)];
            off2[g] = o;
            #pragma unroll
            for (int x = 0; x < NXCD; ++x) {
                int c = cnt2x[(size_t)x * str2 + g];
                base2[(size_t)x * str2 + g] = o;
                o += c;
            }
        }
    }
    if (gid == 0) { off1[n1] = nnz; off2[n2] = nnz; }
}

// ---------------------------------------------------------------------------
// k_fill2: srcs[base[x][d] + rank] = src[i]. No atomics; fire-and-forget.
// ---------------------------------------------------------------------------
__global__ __launch_bounds__(256)
void k_fill2(const int* __restrict__ g1d, const int* __restrict__ g1s,
             const int* __restrict__ base1, const int* __restrict__ rank1,
             int* __restrict__ srcs1,
             const int* __restrict__ g2d, const int* __restrict__ g2s,
             const int* __restrict__ base2, const int* __restrict__ rank2,
             int* __restrict__ srcs2,
             int nnz, int nq, int str1, int str2) {
    int gid = blockIdx.x * 256 + threadIdx.x;
    const int* dst; const int* src; const int* base; const int* rank; int* out; int q; int str;
    if (gid < nq) { dst = g1d; src = g1s; base = base1; rank = rank1; out = srcs1; str = str1; q = gid; }
    else {
        q = gid - nq;
        if (q >= nq) return;
        dst = g2d; src = g2s; base = base2; rank = rank2; out = srcs2; str = str2;
    }
    int i = q << 2;
    if (i + 4 <= nnz) {
        int4 d = *(const int4*)(dst + i);
        int4 s = *(const int4*)(src + i);
        int4 r = *(const int4*)(rank + i);
        int o0 = base[(size_t)((unsigned)r.x >> 24) * str + d.x] + (r.x & 0xFFFFFF);
        int o1 = base[(size_t)((unsigned)r.y >> 24) * str + d.y] + (r.y & 0xFFFFFF);
        int o2 = base[(size_t)((unsigned)r.z >> 24) * str + d.z] + (r.z & 0xFFFFFF);
        int o3 = base[(size_t)((unsigned)r.w >> 24) * str + d.w] + (r.w & 0xFFFFFF);
        out[o0] = s.x;
        out[o1] = s.y;
        out[o2] = s.z;
        out[o3] = s.w;
    } else {
        for (; i < nnz; ++i) {
            int pr = rank[i];
            out[base[(size_t)((unsigned)pr >> 24) * str + dst[i]] + (pr & 0xFFFFFF)] = src[i];
        }
    }
}

// ---------------------------------------------------------------------------
// k_edge_gather: Xe[e] = degE[e] * sum_{j in seg(e)} X[srcs1[j]]
// half-wave per edge row; float4 per lane; 8-way unrolled.
// ---------------------------------------------------------------------------
__global__ __launch_bounds__(256)
void k_edge_gather(const float* __restrict__ X, const int* __restrict__ off,
                   const int* __restrict__ srcs, const float* __restrict__ degE,
                   float* __restrict__ Xe, int n_edges) {
    int gid = blockIdx.x * 256 + threadIdx.x;
    int e = gid >> 5;
    if (e >= n_edges) return;
    int k = (gid & 31) << 2;
    int beg = off[e], end = off[e + 1];
    float4 acc0 = {0, 0, 0, 0}, acc1 = {0, 0, 0, 0};
    float4 acc2 = {0, 0, 0, 0}, acc3 = {0, 0, 0, 0};
    int j = beg;
    for (; j + 8 <= end; j += 8) {
        int s0 = srcs[j + 0];
        int s1 = srcs[j + 1];
        int s2 = srcs[j + 2];
        int s3 = srcs[j + 3];
        int s4 = srcs[j + 4];
        int s5 = srcs[j + 5];
        int s6 = srcs[j + 6];
        int s7 = srcs[j + 7];
        float4 v0 = *(const float4*)(X + (size_t)s0 * DD + k);
        float4 v1 = *(const float4*)(X + (size_t)s1 * DD + k);
        float4 v2 = *(const float4*)(X + (size_t)s2 * DD + k);
        float4 v3 = *(const float4*)(X + (size_t)s3 * DD + k);
        float4 v4 = *(const float4*)(X + (size_t)s4 * DD + k);
        float4 v5 = *(const float4*)(X + (size_t)s5 * DD + k);
        float4 v6 = *(const float4*)(X + (size_t)s6 * DD + k);
        float4 v7 = *(const float4*)(X + (size_t)s7 * DD + k);
        acc0.x += v0.x; acc0.y += v0.y; acc0.z += v0.z; acc0.w += v0.w;
        acc1.x += v1.x; acc1.y += v1.y; acc1.z += v1.z; acc1.w += v1.w;
        acc2.x += v2.x; acc2.y += v2.y; acc2.z += v2.z; acc2.w += v2.w;
        acc3.x += v3.x; acc3.y += v3.y; acc3.z += v3.z; acc3.w += v3.w;
        acc0.x += v4.x; acc0.y += v4.y; acc0.z += v4.z; acc0.w += v4.w;
        acc1.x += v5.x; acc1.y += v5.y; acc1.z += v5.z; acc1.w += v5.w;
        acc2.x += v6.x; acc2.y += v6.y; acc2.z += v6.z; acc2.w += v6.w;
        acc3.x += v7.x; acc3.y += v7.y; acc3.z += v7.z; acc3.w += v7.w;
    }
    for (; j < end; ++j) {
        int s = srcs[j];
        float4 v = *(const float4*)(X + (size_t)s * DD + k);
        acc0.x += v.x; acc0.y += v.y; acc0.z += v.z; acc0.w += v.w;
    }
    float f = degE[e];
    float4 o;
    o.x = f * ((acc0.x + acc1.x) + (acc2.x + acc3.x));
    o.y = f * ((acc0.y + acc1.y) + (acc2.y + acc3.y));
    o.z = f * ((acc0.z + acc1.z) + (acc2.z + acc3.z));
    o.w = f * ((acc0.w + acc1.w) + (acc2.w + acc3.w));
    *(float4*)(Xe + (size_t)e * DD + k) = o;
}

// ---------------------------------------------------------------------------
// k_node_gather: Xi[v] = (1-a)*degV[v] * sum Xe[srcs2[j]] + a*X0[v]  (-> d_out)
// ---------------------------------------------------------------------------
__global__ __launch_bounds__(256)
void k_node_gather(const float* __restrict__ Xe, const int* __restrict__ off,
                   const int* __restrict__ srcs, const float* __restrict__ degV,
                   const float* __restrict__ X0, const float* __restrict__ alphaP,
                   float* __restrict__ Xi, int n_nodes) {
    int gid = blockIdx.x * 256 + threadIdx.x;
    int v = gid >> 5;
    if (v >= n_nodes) return;
    int k = (gid & 31) << 2;
    int beg = off[v], end = off[v + 1];
    float4 acc0 = {0, 0, 0, 0}, acc1 = {0, 0, 0, 0};
    int j = beg;
    for (; j + 4 <= end; j += 4) {
        int s0 = srcs[j + 0];
        int s1 = srcs[j + 1];
        int s2 = srcs[j + 2];
        int s3 = srcs[j + 3];
        float4 v0 = *(const float4*)(Xe + (size_t)s0 * DD + k);
        float4 v1 = *(const float4*)(Xe + (size_t)s1 * DD + k);
        float4 v2 = *(const float4*)(Xe + (size_t)s2 * DD + k);
        float4 v3 = *(const float4*)(Xe + (size_t)s3 * DD + k);
        acc0.x += v0.x; acc0.y += v0.y; acc0.z += v0.z; acc0.w += v0.w;
        acc1.x += v1.x; acc1.y += v1.y; acc1.z += v1.z; acc1.w += v1.w;
        acc0.x += v2.x; acc0.y += v2.y; acc0.z += v2.z; acc0.w += v2.w;
        acc1.x += v3.x; acc1.y += v3.y; acc1.z += v3.z; acc1.w += v3.w;
    }
    for (; j < end; ++j) {
        int s = srcs[j];
        float4 x = *(const float4*)(Xe + (size_t)s * DD + k);
        acc0.x += x.x; acc0.y += x.y; acc0.z += x.z; acc0.w += x.w;
    }
    float a = alphaP[0];
    float f = (1.0f - a) * degV[v];
    float4 x0 = *(const float4*)(X0 + (size_t)v * DD + k);
    float4 o;
    o.x = f * (acc0.x + acc1.x) + a * x0.x;
    o.y = f * (acc0.y + acc1.y) + a * x0.y;
    o.z = f * (acc0.z + acc1.z) + a * x0.z;
    o.w = f * (acc0.w + acc1.w) + a * x0.w;
    *(float4*)(Xi + (size_t)v * DD + k) = o;
}

// ---------------------------------------------------------------------------
// k_prep_w: M'[c][k] = bf16( b*W[c][k] + (1-b)*(c==k) ), row-major [128][128].
// ---------------------------------------------------------------------------
__global__ __launch_bounds__(256)
void k_prep_w(const float* __restrict__ W, const float* __restrict__ betaP,
              short* __restrict__ Mbf) {
    int gid = blockIdx.x * 256 + threadIdx.x;   // 2048 threads, 8 elems each
    if (gid >= DD * DD / 8) return;
    int c  = gid >> 4;
    int k0 = (gid & 15) << 3;
    float b = betaP[0], ib = 1.0f - b;
    const float* p = W + c * DD + k0;
    float4 lo = *(const float4*)p, hi = *(const float4*)(p + 4);
    float v[8] = {lo.x, lo.y, lo.z, lo.w, hi.x, hi.y, hi.z, hi.w};
    bf16x8 t;
    #pragma unroll
    for (int j = 0; j < 8; ++j) {
        float m = b * v[j] + ((k0 + j) == c ? ib : 0.0f);
        t[j] = f2bf(m);
    }
    *(bf16x8*)(Mbf + (size_t)c * DD + k0) = t;
}

// ---------------------------------------------------------------------------
// k_gemm_mfma: out = Xi @ M'^T in place (xio = Xi = out), bf16 MFMA.
// ---------------------------------------------------------------------------
__global__ __launch_bounds__(256)
void k_gemm_mfma(float* xio, const short* __restrict__ Mbf, int n_rows) {
    const int lane = threadIdx.x & 63;
    const int wid  = threadIdx.x >> 6;
    const int m16  = lane & 15;
    const int quad = lane >> 4;
    const int kq   = quad * 8;

    const int strip = blockIdx.x * 4 + wid;
    const int row0 = strip * 16;
    if (row0 >= n_rows) return;

    int arow = row0 + m16;
    if (arow >= n_rows) arow = n_rows - 1;       // inert when M%16==0
    const float* xr = xio + (size_t)arow * DD;

    bf16x8 af[4];
    #pragma unroll
    for (int kf = 0; kf < 4; ++kf) {
        const float* p = xr + kf * 32 + kq;
        float4 lo = *(const float4*)p;
        float4 hi = *(const float4*)(p + 4);
        bf16x8 t;
        t[0] = f2bf(lo.x); t[1] = f2bf(lo.y); t[2] = f2bf(lo.z); t[3] = f2bf(lo.w);
        t[4] = f2bf(hi.x); t[5] = f2bf(hi.y); t[6] = f2bf(hi.z); t[7] = f2bf(hi.w);
        af[kf] = t;
    }

    #pragma unroll
    for (int nt = 0; nt < 8; ++nt) {
        const short* mr = Mbf + (size_t)(nt * 16 + m16) * DD + kq;
        f32x4 acc = {0.f, 0.f, 0.f, 0.f};
        #pragma unroll
        for (int kf = 0; kf < 4; ++kf) {
            bf16x8 bfrag = *(const bf16x8*)(mr + kf * 32);
            acc = __builtin_amdgcn_mfma_f32_16x16x32_bf16(af[kf], bfrag, acc, 0, 0, 0);
        }
        const int col = nt * 16 + m16;
        #pragma unroll
        for (int r = 0; r < 4; ++r) {
            int row = row0 + quad * 4 + r;
            if (row < n_rows)
                xio[(size_t)row * DD + col] = acc[r];
        }
    }
}

// ---------------------------------------------------------------------------
extern "C" void kernel_launch(void* const* d_in, const int* in_sizes, int n_in,
                              void* d_out, int out_size, void* d_ws, size_t ws_size,
                              hipStream_t stream) {
    const float* X     = (const float*)d_in[0];
    const float* X0    = (const float*)d_in[1];
    const float* degE  = (const float*)d_in[2];
    const float* degV  = (const float*)d_in[3];
    const float* alpha = (const float*)d_in[4];
    const float* beta  = (const float*)d_in[5];
    const float* W     = (const float*)d_in[6];
    const int*   g1s   = (const int*)d_in[7];
    const int*   g1d   = (const int*)d_in[8];
    const int*   g2s   = (const int*)d_in[9];
    const int*   g2d   = (const int*)d_in[10];
    float* out = (float*)d_out;

    const int n_nodes = in_sizes[3];        // 100000
    const int n_edges = in_sizes[2];        // 20000
    const int nnz     = in_sizes[7];        // 800000

    // per-XCD counter copy strides, rounded to a 64B line so no line is ever
    // dirty in two different XCDs' L2s (non-coherent!)
    const int str1 = (n_edges + 15) & ~15;  // 20000
    const int str2 = (n_nodes + 15) & ~15;  // 100000

    // --- workspace layout (4-byte units) ---
    // Xe region (n_edges*128 = 2.56M words) overlays rank1(0.8M) + rank2(0.8M)
    // + base1(8*str1=0.16M) + base2(8*str2=0.8M) = 2.56M exactly — all dead
    // before k_edge_gather writes Xe.
    // 8-copy counters (0.96M words) overlay srcs1/srcs2 (1.6M) — dead after
    // k_scan_add2, before k_fill2 writes srcs.
    int*   wsi   = (int*)d_ws;
    float* Xe    = (float*)d_ws;                       // [E*128] (10.24 MB)
    int*   rank1 = wsi;                                // [nnz]
    int*   rank2 = wsi + nnz;                          // [nnz]
    int*   base1 = wsi + 2 * (size_t)nnz;              // [8*str1]
    int*   base2 = base1 + (size_t)NXCD * str1;        // [8*str2]
    size_t o     = (size_t)n_edges * DD;
    int*   off1  = wsi + o;          o += n_edges + 1;
    int*   off2  = wsi + o;          o += n_nodes + 1;
    size_t srcs_base = o;
    int*   srcs1 = wsi + o;          o += nnz;
    int*   srcs2 = wsi + o;          o += nnz;
    int*   bsum  = wsi + o;          o += 128;
    short* Mbf   = (short*)(wsi + o); o += DD * DD / 2;  // bf16 [128][128]
    int*   cnt1x = wsi + srcs_base;                    // [8*str1] overlays srcs
    int*   cnt2x = cnt1x + (size_t)NXCD * str1;        // [8*str2]

    // zero the 8-copy counters (contiguous): 8*(20000+100000) ints = 3.84 MB
    hipMemsetAsync(cnt1x, 0,
                   (size_t)NXCD * (str1 + str2) * sizeof(int), stream);

    const int nb1 = (n_edges + SCAN_CHUNK - 1) / SCAN_CHUNK;   // 10
    const int nb2 = (n_nodes + SCAN_CHUNK - 1) / SCAN_CHUNK;   // 49
    const int no  = (nnz + 7) / 8;                             // octs per graph
    const int oblb = (2 * no + 255) / 256;
    const int nq  = (nnz + 3) / 4;                             // quads per graph
    const int qblb = (2 * nq + 255) / 256;

    // ---- fold (1-b)I + bW^T into bf16 M' (reused by the final GEMM) ----
    k_prep_w<<<(DD * DD / 8 + 255) / 256, 256, 0, stream>>>(W, beta, Mbf);

    // ---- fused CSR build for g1 (dst=hyperedge) and g2 (dst=node) ----
    k_hist2<<<oblb, 256, 0, stream>>>(g1d, g2d, cnt1x, cnt2x, rank1, rank2,
                                      nnz, no, str1, str2);
    k_scan_blocks2<<<nb1 + nb2, 256, 0, stream>>>(cnt1x, off1, cnt2x, off2, bsum,
                                                  n_edges, n_nodes, nb1, str1, str2);
    k_scan_top2<<<1, 64, 0, stream>>>(bsum, nb1, nb2);
    k_scan_add2<<<(n_edges + n_nodes + 255) / 256, 256, 0, stream>>>(
        off1, off2, bsum, cnt1x, base1, cnt2x, base2,
        n_edges, n_nodes, str1, str2, nnz);
    k_fill2<<<qblb, 256, 0, stream>>>(g1d, g1s, base1, rank1, srcs1,
                                      g2d, g2s, base2, rank2, srcs2,
                                      nnz, nq, str1, str2);

    // ---- gather phases ----
    k_edge_gather<<<(n_edges * 32 + 255) / 256, 256, 0, stream>>>(
        X, off1, srcs1, degE, Xe, n_edges);
    k_node_gather<<<(n_nodes * 32 + 255) / 256, 256, 0, stream>>>(
        Xe, off2, srcs2, degV, X0, alpha, out, n_nodes);

    // ---- out = Xi @ M'^T, in place, bf16 MFMA ----
    const int nstrips = (n_nodes + 15) / 16;           // 6250
    k_gemm_mfma<<<(nstrips + 3) / 4, 256, 0, stream>>>(out, Mbf, n_nodes);
}

// Round 2
// 391.594 us; speedup vs baseline: 1.0544x; 1.0544x over previous
//
#include <hip/hip_runtime.h>

#define DD 128
#define SCAN_CHUNK 2048   // 256 threads x 8 elements per scan block
#define PAD1 16           // cnt1 stride: one counter per 64B line
#define PAD2 8            // cnt2 stride: two counters per 64B line

typedef __attribute__((ext_vector_type(8))) short bf16x8;
typedef __attribute__((ext_vector_type(4))) short bf16x4;
typedef __attribute__((ext_vector_type(4))) float f32x4;

__device__ __forceinline__ short f2bf(float f) {
    union { float f; unsigned u; } x; x.f = f;
    unsigned r = x.u + 0x7FFF + ((x.u >> 16) & 1);   // round-to-nearest-even
    return (short)(r >> 16);
}
__device__ __forceinline__ float bf2f(short h) {
    union { float f; unsigned u; } x;
    x.u = ((unsigned)(unsigned short)h) << 16;
    return x.f;
}

// ---------------------------------------------------------------------------
// k_hist1: blocks [0,8): fold (1-b)I + b*W into bf16 M' (prep_w).
//          blocks [8,..): histogram g1 into padded counters, capture ranks.
// Returning global atomics execute memory-side on gfx950 (measured: scope
// changes don't alter WRITE_SIZE) -> plain atomicAdd, 8 independent
// chains/thread for latency cover.
// ---------------------------------------------------------------------------
__global__ __launch_bounds__(256)
void k_hist1(const int* __restrict__ g1d, int* __restrict__ cnt1p,
             int* __restrict__ rank1, int nnz, int no,
             const float* __restrict__ W, const float* __restrict__ betaP,
             short* __restrict__ Mbf) {
    if (blockIdx.x < 8) {                      // ---- prep_w path ----
        int gid = blockIdx.x * 256 + threadIdx.x;   // 2048 threads, 8 elems each
        if (gid >= DD * DD / 8) return;
        int c  = gid >> 4;
        int k0 = (gid & 15) << 3;
        float b = betaP[0], ib = 1.0f - b;
        const float* p = W + c * DD + k0;
        float4 lo = *(const float4*)p, hi = *(const float4*)(p + 4);
        float v[8] = {lo.x, lo.y, lo.z, lo.w, hi.x, hi.y, hi.z, hi.w};
        bf16x8 t;
        #pragma unroll
        for (int j = 0; j < 8; ++j) {
            float m = b * v[j] + ((k0 + j) == c ? ib : 0.0f);
            t[j] = f2bf(m);
        }
        *(bf16x8*)(Mbf + (size_t)c * DD + k0) = t;
        return;
    }
    int q = (blockIdx.x - 8) * 256 + threadIdx.x;
    if (q >= no) return;
    int i = q << 3;
    if (i + 8 <= nnz) {
        int4 d0 = *(const int4*)(g1d + i);
        int4 d1 = *(const int4*)(g1d + i + 4);
        int r0 = atomicAdd(&cnt1p[d0.x * PAD1], 1);
        int r1 = atomicAdd(&cnt1p[d0.y * PAD1], 1);
        int r2 = atomicAdd(&cnt1p[d0.z * PAD1], 1);
        int r3 = atomicAdd(&cnt1p[d0.w * PAD1], 1);
        int r4 = atomicAdd(&cnt1p[d1.x * PAD1], 1);
        int r5 = atomicAdd(&cnt1p[d1.y * PAD1], 1);
        int r6 = atomicAdd(&cnt1p[d1.z * PAD1], 1);
        int r7 = atomicAdd(&cnt1p[d1.w * PAD1], 1);
        *(int4*)(rank1 + i)     = make_int4(r0, r1, r2, r3);
        *(int4*)(rank1 + i + 4) = make_int4(r4, r5, r6, r7);
    } else {
        for (; i < nnz; ++i) rank1[i] = atomicAdd(&cnt1p[g1d[i] * PAD1], 1);
    }
}

// ---------------------------------------------------------------------------
// k_scan_blocks: chunk-local exclusive scan of padded counters -> off[],
// per-chunk totals -> bsum[b].
// ---------------------------------------------------------------------------
__global__ __launch_bounds__(256)
void k_scan_blocks(const int* __restrict__ cnt, int* __restrict__ off,
                   int* __restrict__ bsum, int n, int str) {
    __shared__ int sh[256];
    const int tid = threadIdx.x;
    const int base = blockIdx.x * SCAN_CHUNK + tid * 8;
    int v[8];
    int s = 0;
    #pragma unroll
    for (int j = 0; j < 8; ++j) {
        int idx = base + j;
        v[j] = (idx < n) ? cnt[(size_t)idx * str] : 0;
        s += v[j];
    }
    sh[tid] = s;
    __syncthreads();
    for (int d = 1; d < 256; d <<= 1) {
        int y = (tid >= d) ? sh[tid - d] : 0;
        __syncthreads();
        sh[tid] += y;
        __syncthreads();
    }
    int incl = sh[tid];
    int run = incl - s;
    #pragma unroll
    for (int j = 0; j < 8; ++j) {
        int idx = base + j;
        if (idx < n) off[idx] = run;
        run += v[j];
    }
    if (tid == 255) bsum[blockIdx.x] = incl;      // chunk total (inclusive)
}

// ---------------------------------------------------------------------------
// k_scan_add: off[gid] += sum of bsum[0..chunk); inlined top-level scan
// (nb <= 49, trivial redundant loop per thread).
// ---------------------------------------------------------------------------
__global__ __launch_bounds__(256)
void k_scan_add(int* __restrict__ off, const int* __restrict__ bsum,
                int n, int nnz) {
    int gid = blockIdx.x * 256 + threadIdx.x;
    if (gid == 0) off[n] = nnz;
    if (gid >= n) return;
    int chunk = gid >> 11;                        // SCAN_CHUNK == 2048
    int p = 0;
    for (int i = 0; i < chunk; ++i) p += bsum[i];
    off[gid] += p;
}

// ---------------------------------------------------------------------------
// k_fill: srcs[off[d] + rank[i]] = src[i]. No atomics; fire-and-forget.
// ---------------------------------------------------------------------------
__global__ __launch_bounds__(256)
void k_fill(const int* __restrict__ dst, const int* __restrict__ src,
            const int* __restrict__ off, const int* __restrict__ rank,
            int* __restrict__ out, int nnz, int str) {
    int q = blockIdx.x * 256 + threadIdx.x;
    int i = q << 2;
    if (i + 4 <= nnz) {
        int4 d = *(const int4*)(dst + i);
        int4 s = *(const int4*)(src + i);
        int4 r = *(const int4*)(rank + i);
        int o0 = off[d.x];
        int o1 = off[d.y];
        int o2 = off[d.z];
        int o3 = off[d.w];
        out[o0 + r.x] = s.x;
        out[o1 + r.y] = s.y;
        out[o2 + r.z] = s.z;
        out[o3 + r.w] = s.w;
    } else {
        for (; i < nnz; ++i) out[off[dst[i]] + rank[i]] = src[i];
    }
    (void)str;
}

// ---------------------------------------------------------------------------
// k_h2_egather: fused kernel.
//   blocks [0,H):  histogram g2 (atomic/latency-bound, no upstream deps)
//   blocks [H,..): edge gather Xe[e] = degE[e] * sum X[srcs1[j]]  -> bf16
// The hist blocks ride under the gather's memory time: complementary pipes
// (EA atomic transactions vs read bandwidth).
// ---------------------------------------------------------------------------
__global__ __launch_bounds__(256)
void k_h2_egather(const int* __restrict__ g2d, int* __restrict__ cnt2p,
                  int* __restrict__ rank2, int nnz, int no, int H,
                  const float* __restrict__ X, const int* __restrict__ off1,
                  const int* __restrict__ srcs1, const float* __restrict__ degE,
                  short* __restrict__ XeBF, int n_edges) {
    if (blockIdx.x < H) {                         // ---- hist g2 path ----
        int q = blockIdx.x * 256 + threadIdx.x;
        if (q >= no) return;
        int i = q << 3;
        if (i + 8 <= nnz) {
            int4 d0 = *(const int4*)(g2d + i);
            int4 d1 = *(const int4*)(g2d + i + 4);
            int r0 = atomicAdd(&cnt2p[d0.x * PAD2], 1);
            int r1 = atomicAdd(&cnt2p[d0.y * PAD2], 1);
            int r2 = atomicAdd(&cnt2p[d0.z * PAD2], 1);
            int r3 = atomicAdd(&cnt2p[d0.w * PAD2], 1);
            int r4 = atomicAdd(&cnt2p[d1.x * PAD2], 1);
            int r5 = atomicAdd(&cnt2p[d1.y * PAD2], 1);
            int r6 = atomicAdd(&cnt2p[d1.z * PAD2], 1);
            int r7 = atomicAdd(&cnt2p[d1.w * PAD2], 1);
            *(int4*)(rank2 + i)     = make_int4(r0, r1, r2, r3);
            *(int4*)(rank2 + i + 4) = make_int4(r4, r5, r6, r7);
        } else {
            for (; i < nnz; ++i) rank2[i] = atomicAdd(&cnt2p[g2d[i] * PAD2], 1);
        }
        return;
    }
    // ---- edge gather path ----
    int gid = (blockIdx.x - H) * 256 + threadIdx.x;
    int e = gid >> 5;
    if (e >= n_edges) return;
    int k = (gid & 31) << 2;
    int beg = off1[e], end = off1[e + 1];
    float4 acc0 = {0, 0, 0, 0}, acc1 = {0, 0, 0, 0};
    float4 acc2 = {0, 0, 0, 0}, acc3 = {0, 0, 0, 0};
    int j = beg;
    for (; j + 8 <= end; j += 8) {
        int s0 = srcs1[j + 0];
        int s1 = srcs1[j + 1];
        int s2 = srcs1[j + 2];
        int s3 = srcs1[j + 3];
        int s4 = srcs1[j + 4];
        int s5 = srcs1[j + 5];
        int s6 = srcs1[j + 6];
        int s7 = srcs1[j + 7];
        float4 v0 = *(const float4*)(X + (size_t)s0 * DD + k);
        float4 v1 = *(const float4*)(X + (size_t)s1 * DD + k);
        float4 v2 = *(const float4*)(X + (size_t)s2 * DD + k);
        float4 v3 = *(const float4*)(X + (size_t)s3 * DD + k);
        float4 v4 = *(const float4*)(X + (size_t)s4 * DD + k);
        float4 v5 = *(const float4*)(X + (size_t)s5 * DD + k);
        float4 v6 = *(const float4*)(X + (size_t)s6 * DD + k);
        float4 v7 = *(const float4*)(X + (size_t)s7 * DD + k);
        acc0.x += v0.x; acc0.y += v0.y; acc0.z += v0.z; acc0.w += v0.w;
        acc1.x += v1.x; acc1.y += v1.y; acc1.z += v1.z; acc1.w += v1.w;
        acc2.x += v2.x; acc2.y += v2.y; acc2.z += v2.z; acc2.w += v2.w;
        acc3.x += v3.x; acc3.y += v3.y; acc3.z += v3.z; acc3.w += v3.w;
        acc0.x += v4.x; acc0.y += v4.y; acc0.z += v4.z; acc0.w += v4.w;
        acc1.x += v5.x; acc1.y += v5.y; acc1.z += v5.z; acc1.w += v5.w;
        acc2.x += v6.x; acc2.y += v6.y; acc2.z += v6.z; acc2.w += v6.w;
        acc3.x += v7.x; acc3.y += v7.y; acc3.z += v7.z; acc3.w += v7.w;
    }
    for (; j < end; ++j) {
        int s = srcs1[j];
        float4 v = *(const float4*)(X + (size_t)s * DD + k);
        acc0.x += v.x; acc0.y += v.y; acc0.z += v.z; acc0.w += v.w;
    }
    float f = degE[e];
    bf16x4 ob;
    ob[0] = f2bf(f * ((acc0.x + acc1.x) + (acc2.x + acc3.x)));
    ob[1] = f2bf(f * ((acc0.y + acc1.y) + (acc2.y + acc3.y)));
    ob[2] = f2bf(f * ((acc0.z + acc1.z) + (acc2.z + acc3.z)));
    ob[3] = f2bf(f * ((acc0.w + acc1.w) + (acc2.w + acc3.w)));
    *(bf16x4*)(XeBF + (size_t)e * DD + k) = ob;
}

// ---------------------------------------------------------------------------
// k_node_gather: Xi[v] = (1-a)*degV[v] * sum XeBF[srcs2[j]] + a*X0[v] (-> out)
// XeBF is bf16: 8B per lane per row (half-wave covers the 256B row).
// ---------------------------------------------------------------------------
__global__ __launch_bounds__(256)
void k_node_gather(const short* __restrict__ XeBF, const int* __restrict__ off,
                   const int* __restrict__ srcs, const float* __restrict__ degV,
                   const float* __restrict__ X0, const float* __restrict__ alphaP,
                   float* __restrict__ Xi, int n_nodes) {
    int gid = blockIdx.x * 256 + threadIdx.x;
    int v = gid >> 5;
    if (v >= n_nodes) return;
    int k = (gid & 31) << 2;
    int beg = off[v], end = off[v + 1];
    float4 acc0 = {0, 0, 0, 0}, acc1 = {0, 0, 0, 0};
    int j = beg;
    for (; j + 4 <= end; j += 4) {
        int s0 = srcs[j + 0];
        int s1 = srcs[j + 1];
        int s2 = srcs[j + 2];
        int s3 = srcs[j + 3];
        bf16x4 h0 = *(const bf16x4*)(XeBF + (size_t)s0 * DD + k);
        bf16x4 h1 = *(const bf16x4*)(XeBF + (size_t)s1 * DD + k);
        bf16x4 h2 = *(const bf16x4*)(XeBF + (size_t)s2 * DD + k);
        bf16x4 h3 = *(const bf16x4*)(XeBF + (size_t)s3 * DD + k);
        acc0.x += bf2f(h0[0]); acc0.y += bf2f(h0[1]); acc0.z += bf2f(h0[2]); acc0.w += bf2f(h0[3]);
        acc1.x += bf2f(h1[0]); acc1.y += bf2f(h1[1]); acc1.z += bf2f(h1[2]); acc1.w += bf2f(h1[3]);
        acc0.x += bf2f(h2[0]); acc0.y += bf2f(h2[1]); acc0.z += bf2f(h2[2]); acc0.w += bf2f(h2[3]);
        acc1.x += bf2f(h3[0]); acc1.y += bf2f(h3[1]); acc1.z += bf2f(h3[2]); acc1.w += bf2f(h3[3]);
    }
    for (; j < end; ++j) {
        int s = srcs[j];
        bf16x4 h = *(const bf16x4*)(XeBF + (size_t)s * DD + k);
        acc0.x += bf2f(h[0]); acc0.y += bf2f(h[1]); acc0.z += bf2f(h[2]); acc0.w += bf2f(h[3]);
    }
    float a = alphaP[0];
    float f = (1.0f - a) * degV[v];
    float4 x0 = *(const float4*)(X0 + (size_t)v * DD + k);
    float4 o;
    o.x = f * (acc0.x + acc1.x) + a * x0.x;
    o.y = f * (acc0.y + acc1.y) + a * x0.y;
    o.z = f * (acc0.z + acc1.z) + a * x0.z;
    o.w = f * (acc0.w + acc1.w) + a * x0.w;
    *(float4*)(Xi + (size_t)v * DD + k) = o;
}

// ---------------------------------------------------------------------------
// k_gemm_mfma: out = Xi @ M'^T in place (xio = Xi = out), bf16 MFMA.
// One wave per 16-row strip; B-frags direct loads from M' (32 KB, L1-hot);
// C/D layout col=lane&15, row=quad*4+reg. Identity folded into M'.
// ---------------------------------------------------------------------------
__global__ __launch_bounds__(256)
void k_gemm_mfma(float* xio, const short* __restrict__ Mbf, int n_rows) {
    const int lane = threadIdx.x & 63;
    const int wid  = threadIdx.x >> 6;
    const int m16  = lane & 15;
    const int quad = lane >> 4;
    const int kq   = quad * 8;

    const int strip = blockIdx.x * 4 + wid;
    const int row0 = strip * 16;
    if (row0 >= n_rows) return;

    int arow = row0 + m16;
    if (arow >= n_rows) arow = n_rows - 1;       // inert when M%16==0
    const float* xr = xio + (size_t)arow * DD;

    bf16x8 af[4];
    #pragma unroll
    for (int kf = 0; kf < 4; ++kf) {
        const float* p = xr + kf * 32 + kq;
        float4 lo = *(const float4*)p;
        float4 hi = *(const float4*)(p + 4);
        bf16x8 t;
        t[0] = f2bf(lo.x); t[1] = f2bf(lo.y); t[2] = f2bf(lo.z); t[3] = f2bf(lo.w);
        t[4] = f2bf(hi.x); t[5] = f2bf(hi.y); t[6] = f2bf(hi.z); t[7] = f2bf(hi.w);
        af[kf] = t;
    }

    #pragma unroll
    for (int nt = 0; nt < 8; ++nt) {
        const short* mr = Mbf + (size_t)(nt * 16 + m16) * DD + kq;
        f32x4 acc = {0.f, 0.f, 0.f, 0.f};
        #pragma unroll
        for (int kf = 0; kf < 4; ++kf) {
            bf16x8 bfrag = *(const bf16x8*)(mr + kf * 32);
            acc = __builtin_amdgcn_mfma_f32_16x16x32_bf16(af[kf], bfrag, acc, 0, 0, 0);
        }
        const int col = nt * 16 + m16;
        #pragma unroll
        for (int r = 0; r < 4; ++r) {
            int row = row0 + quad * 4 + r;
            if (row < n_rows)
                xio[(size_t)row * DD + col] = acc[r];
        }
    }
}

// ---------------------------------------------------------------------------
extern "C" void kernel_launch(void* const* d_in, const int* in_sizes, int n_in,
                              void* d_out, int out_size, void* d_ws, size_t ws_size,
                              hipStream_t stream) {
    const float* X     = (const float*)d_in[0];
    const float* X0    = (const float*)d_in[1];
    const float* degE  = (const float*)d_in[2];
    const float* degV  = (const float*)d_in[3];
    const float* alpha = (const float*)d_in[4];
    const float* beta  = (const float*)d_in[5];
    const float* W     = (const float*)d_in[6];
    const int*   g1s   = (const int*)d_in[7];
    const int*   g1d   = (const int*)d_in[8];
    const int*   g2s   = (const int*)d_in[9];
    const int*   g2d   = (const int*)d_in[10];
    float* out = (float*)d_out;

    const int n_nodes = in_sizes[3];        // 100000
    const int n_edges = in_sizes[2];        // 20000
    const int nnz     = in_sizes[7];        // 800000

    // --- workspace layout (4-byte units) ---
    // XeBF (bf16 [E][128], 1.28M words) written by the fused kernel.
    // rank1/rank2 SHARE one slot right after XeBF (rank1 dead after k_fill(g1),
    // rank2 written by the fused kernel afterwards).
    // cnt1p overlays srcs1 (dead until fill1, after scan1); cnt2p overlays
    // srcs2 exactly (100000*PAD2 == nnz), dead after scan2, before fill2.
    int*   wsi   = (int*)d_ws;
    short* XeBF  = (short*)d_ws;                       // [E*128] bf16 (5.12 MB)
    size_t o     = (size_t)n_edges * DD / 2;           // words
    int*   rank1 = wsi + o;                            // [nnz]
    int*   rank2 = rank1;                              // shared slot
    o += nnz;
    int*   off1  = wsi + o;          o += n_edges + 1;
    int*   off2  = wsi + o;          o += n_nodes + 1;
    size_t srcs_base = o;
    int*   srcs1 = wsi + o;          o += nnz;
    int*   srcs2 = wsi + o;          o += nnz;
    int*   bsum  = wsi + o;          o += 64;
    short* Mbf   = (short*)(wsi + o); o += DD * DD / 2;  // bf16 [128][128]
    int*   cnt1p = wsi + srcs_base;                    // [n_edges*PAD1]
    int*   cnt2p = wsi + srcs_base + nnz;              // [n_nodes*PAD2] == srcs2

    // zero both padded counter regions (they live inside srcs1/srcs2)
    hipMemsetAsync(cnt1p, 0, 2 * (size_t)nnz * sizeof(int), stream);

    const int nb1 = (n_edges + SCAN_CHUNK - 1) / SCAN_CHUNK;   // 10
    const int nb2 = (n_nodes + SCAN_CHUNK - 1) / SCAN_CHUNK;   // 49
    const int no  = (nnz + 7) / 8;                             // octs per graph
    const int hb  = (no + 255) / 256;                          // hist blocks: 391
    const int nq  = (nnz + 3) / 4;                             // quads per graph
    const int qb  = (nq + 255) / 256;                          // fill blocks

    // ---- g1 CSR build (prep_w fused into hist1's first 8 blocks) ----
    k_hist1<<<8 + hb, 256, 0, stream>>>(g1d, cnt1p, rank1, nnz, no, W, beta, Mbf);
    k_scan_blocks<<<nb1, 256, 0, stream>>>(cnt1p, off1, bsum, n_edges, PAD1);
    k_scan_add<<<(n_edges + 255) / 256, 256, 0, stream>>>(off1, bsum, n_edges, nnz);
    k_fill<<<qb, 256, 0, stream>>>(g1d, g1s, off1, rank1, srcs1, nnz, PAD1);

    // ---- fused: g2 histogram (no deps) rides under the edge gather ----
    const int egb = (n_edges * 32 + 255) / 256;                // 2500
    k_h2_egather<<<hb + egb, 256, 0, stream>>>(g2d, cnt2p, rank2, nnz, no, hb,
                                               X, off1, srcs1, degE, XeBF, n_edges);

    // ---- g2 CSR finalize ----
    k_scan_blocks<<<nb2, 256, 0, stream>>>(cnt2p, off2, bsum, n_nodes, PAD2);
    k_scan_add<<<(n_nodes + 255) / 256, 256, 0, stream>>>(off2, bsum, n_nodes, nnz);
    k_fill<<<qb, 256, 0, stream>>>(g2d, g2s, off2, rank2, srcs2, nnz, PAD2);

    // ---- node gather (reads bf16 Xe) ----
    k_node_gather<<<(n_nodes * 32 + 255) / 256, 256, 0, stream>>>(
        XeBF, off2, srcs2, degV, X0, alpha, out, n_nodes);

    // ---- out = Xi @ M'^T, in place, bf16 MFMA ----
    const int nstrips = (n_nodes + 15) / 16;           // 6250
    k_gemm_mfma<<<(nstrips + 3) / 4, 256, 0, stream>>>(out, Mbf, n_nodes);
}

// Round 3
// 374.780 us; speedup vs baseline: 1.1017x; 1.0449x over previous
//
#include <hip/hip_runtime.h>

#define DD 128
#define SCAN_CHUNK 2048   // 256 threads x 8 elements per scan block
#define PAD1 16           // cnt1 stride: one counter per 64B line
#define PAD2 8            // cnt2 stride: two counters per 64B line

typedef __attribute__((ext_vector_type(8))) _Float16 f16x8;
typedef __attribute__((ext_vector_type(4))) _Float16 f16x4;
typedef __attribute__((ext_vector_type(4))) float f32x4;

// ---------------------------------------------------------------------------
// k_hist1: three block ranges, all independent:
//   [0, hb)        : histogram g1 into padded counters, capture ranks
//   [hb, hb+8)     : fold (1-b)I + b*W into fp16 M' (prep_w)
//   [hb+8, +cb)    : convert X (fp32) -> Xh (fp16) for the cheap gather
// The conversion's ~77MB of streaming hides under the atomic-latency-bound
// histogram (measured: hist runs at 11% HBM, 0.3% VALU).
// ---------------------------------------------------------------------------
__global__ __launch_bounds__(256)
void k_hist1(const int* __restrict__ g1d, int* __restrict__ cnt1p,
             int* __restrict__ rank1, int nnz, int no, int hb,
             const float* __restrict__ W, const float* __restrict__ betaP,
             _Float16* __restrict__ Mh,
             const float* __restrict__ X, _Float16* __restrict__ Xh, int nx) {
    const int b = blockIdx.x;
    if (b < hb) {                              // ---- hist g1 ----
        int q = b * 256 + threadIdx.x;
        if (q >= no) return;
        int i = q << 3;
        if (i + 8 <= nnz) {
            int4 d0 = *(const int4*)(g1d + i);
            int4 d1 = *(const int4*)(g1d + i + 4);
            int r0 = atomicAdd(&cnt1p[d0.x * PAD1], 1);
            int r1 = atomicAdd(&cnt1p[d0.y * PAD1], 1);
            int r2 = atomicAdd(&cnt1p[d0.z * PAD1], 1);
            int r3 = atomicAdd(&cnt1p[d0.w * PAD1], 1);
            int r4 = atomicAdd(&cnt1p[d1.x * PAD1], 1);
            int r5 = atomicAdd(&cnt1p[d1.y * PAD1], 1);
            int r6 = atomicAdd(&cnt1p[d1.z * PAD1], 1);
            int r7 = atomicAdd(&cnt1p[d1.w * PAD1], 1);
            *(int4*)(rank1 + i)     = make_int4(r0, r1, r2, r3);
            *(int4*)(rank1 + i + 4) = make_int4(r4, r5, r6, r7);
        } else {
            for (; i < nnz; ++i) rank1[i] = atomicAdd(&cnt1p[g1d[i] * PAD1], 1);
        }
        return;
    }
    if (b < hb + 8) {                          // ---- prep_w (fp16 M') ----
        int gid = (b - hb) * 256 + threadIdx.x;     // 2048 threads, 8 elems each
        if (gid >= DD * DD / 8) return;
        int c  = gid >> 4;
        int k0 = (gid & 15) << 3;
        float bb = betaP[0], ib = 1.0f - bb;
        const float* p = W + c * DD + k0;
        float4 lo = *(const float4*)p, hi = *(const float4*)(p + 4);
        float v[8] = {lo.x, lo.y, lo.z, lo.w, hi.x, hi.y, hi.z, hi.w};
        f16x8 t;
        #pragma unroll
        for (int j = 0; j < 8; ++j) {
            float m = bb * v[j] + ((k0 + j) == c ? ib : 0.0f);
            t[j] = (_Float16)m;
        }
        *(f16x8*)(Mh + (size_t)c * DD + k0) = t;
        return;
    }
    // ---- X -> fp16 conversion ----
    int gid = (b - hb - 8) * 256 + threadIdx.x;
    int i = gid << 3;
    if (i + 8 <= nx) {
        float4 lo = *(const float4*)(X + i);
        float4 hi = *(const float4*)(X + i + 4);
        f16x8 t;
        t[0] = (_Float16)lo.x; t[1] = (_Float16)lo.y;
        t[2] = (_Float16)lo.z; t[3] = (_Float16)lo.w;
        t[4] = (_Float16)hi.x; t[5] = (_Float16)hi.y;
        t[6] = (_Float16)hi.z; t[7] = (_Float16)hi.w;
        *(f16x8*)(Xh + i) = t;
    } else {
        for (; i < nx; ++i) Xh[i] = (_Float16)X[i];
    }
}

// ---------------------------------------------------------------------------
// k_scan_blocks: chunk-local exclusive scan of padded counters -> off[],
// per-chunk totals -> bsum[b].
// ---------------------------------------------------------------------------
__global__ __launch_bounds__(256)
void k_scan_blocks(const int* __restrict__ cnt, int* __restrict__ off,
                   int* __restrict__ bsum, int n, int str) {
    __shared__ int sh[256];
    const int tid = threadIdx.x;
    const int base = blockIdx.x * SCAN_CHUNK + tid * 8;
    int v[8];
    int s = 0;
    #pragma unroll
    for (int j = 0; j < 8; ++j) {
        int idx = base + j;
        v[j] = (idx < n) ? cnt[(size_t)idx * str] : 0;
        s += v[j];
    }
    sh[tid] = s;
    __syncthreads();
    for (int d = 1; d < 256; d <<= 1) {
        int y = (tid >= d) ? sh[tid - d] : 0;
        __syncthreads();
        sh[tid] += y;
        __syncthreads();
    }
    int incl = sh[tid];
    int run = incl - s;
    #pragma unroll
    for (int j = 0; j < 8; ++j) {
        int idx = base + j;
        if (idx < n) off[idx] = run;
        run += v[j];
    }
    if (tid == 255) bsum[blockIdx.x] = incl;      // chunk total (inclusive)
}

// ---------------------------------------------------------------------------
// k_scan_add: off[gid] += sum of bsum[0..chunk); nb <= 49 so a redundant
// per-thread loop is cheaper than another launch.
// ---------------------------------------------------------------------------
__global__ __launch_bounds__(256)
void k_scan_add(int* __restrict__ off, const int* __restrict__ bsum,
                int n, int nnz) {
    int gid = blockIdx.x * 256 + threadIdx.x;
    if (gid == 0) off[n] = nnz;
    if (gid >= n) return;
    int chunk = gid >> 11;                        // SCAN_CHUNK == 2048
    int p = 0;
    for (int i = 0; i < chunk; ++i) p += bsum[i];
    off[gid] += p;
}

// ---------------------------------------------------------------------------
// k_fill: srcs[off[d] + rank[i]] = src[i]. No atomics; fire-and-forget.
// ---------------------------------------------------------------------------
__global__ __launch_bounds__(256)
void k_fill(const int* __restrict__ dst, const int* __restrict__ src,
            const int* __restrict__ off, const int* __restrict__ rank,
            int* __restrict__ out, int nnz) {
    int q = blockIdx.x * 256 + threadIdx.x;
    int i = q << 2;
    if (i + 4 <= nnz) {
        int4 d = *(const int4*)(dst + i);
        int4 s = *(const int4*)(src + i);
        int4 r = *(const int4*)(rank + i);
        int o0 = off[d.x];
        int o1 = off[d.y];
        int o2 = off[d.z];
        int o3 = off[d.w];
        out[o0 + r.x] = s.x;
        out[o1 + r.y] = s.y;
        out[o2 + r.z] = s.z;
        out[o3 + r.w] = s.w;
    } else {
        for (; i < nnz; ++i) out[off[dst[i]] + rank[i]] = src[i];
    }
}

// ---------------------------------------------------------------------------
// k_h2_egather: fused kernel.
//   blocks [0,H):  histogram g2 (atomic/latency-bound, no upstream deps)
//   blocks [H,..): edge gather Xe[e] = degE[e] * sum Xh[srcs1[j]]  (fp16 in,
//                  fp32 accum, fp16 out). Quarter-wave (16 lanes x 16B) per
//                  edge row: 256B per row request, half the fp32 traffic.
// ---------------------------------------------------------------------------
__global__ __launch_bounds__(256)
void k_h2_egather(const int* __restrict__ g2d, int* __restrict__ cnt2p,
                  int* __restrict__ rank2, int nnz, int no, int H,
                  const _Float16* __restrict__ Xh, const int* __restrict__ off1,
                  const int* __restrict__ srcs1, const float* __restrict__ degE,
                  _Float16* __restrict__ XeH, int n_edges) {
    if (blockIdx.x < H) {                         // ---- hist g2 path ----
        int q = blockIdx.x * 256 + threadIdx.x;
        if (q >= no) return;
        int i = q << 3;
        if (i + 8 <= nnz) {
            int4 d0 = *(const int4*)(g2d + i);
            int4 d1 = *(const int4*)(g2d + i + 4);
            int r0 = atomicAdd(&cnt2p[d0.x * PAD2], 1);
            int r1 = atomicAdd(&cnt2p[d0.y * PAD2], 1);
            int r2 = atomicAdd(&cnt2p[d0.z * PAD2], 1);
            int r3 = atomicAdd(&cnt2p[d0.w * PAD2], 1);
            int r4 = atomicAdd(&cnt2p[d1.x * PAD2], 1);
            int r5 = atomicAdd(&cnt2p[d1.y * PAD2], 1);
            int r6 = atomicAdd(&cnt2p[d1.z * PAD2], 1);
            int r7 = atomicAdd(&cnt2p[d1.w * PAD2], 1);
            *(int4*)(rank2 + i)     = make_int4(r0, r1, r2, r3);
            *(int4*)(rank2 + i + 4) = make_int4(r4, r5, r6, r7);
        } else {
            for (; i < nnz; ++i) rank2[i] = atomicAdd(&cnt2p[g2d[i] * PAD2], 1);
        }
        return;
    }
    // ---- edge gather path ----
    int gid = (blockIdx.x - H) * 256 + threadIdx.x;
    int e = gid >> 4;
    if (e >= n_edges) return;
    int k = (gid & 15) << 3;                      // cols [k, k+8)
    int beg = off1[e], end = off1[e + 1];
    float a0[8] = {0, 0, 0, 0, 0, 0, 0, 0};
    float a1[8] = {0, 0, 0, 0, 0, 0, 0, 0};
    int j = beg;
    for (; j + 8 <= end; j += 8) {
        int s0 = srcs1[j + 0];
        int s1 = srcs1[j + 1];
        int s2 = srcs1[j + 2];
        int s3 = srcs1[j + 3];
        int s4 = srcs1[j + 4];
        int s5 = srcs1[j + 5];
        int s6 = srcs1[j + 6];
        int s7 = srcs1[j + 7];
        f16x8 v0 = *(const f16x8*)(Xh + (size_t)s0 * DD + k);
        f16x8 v1 = *(const f16x8*)(Xh + (size_t)s1 * DD + k);
        f16x8 v2 = *(const f16x8*)(Xh + (size_t)s2 * DD + k);
        f16x8 v3 = *(const f16x8*)(Xh + (size_t)s3 * DD + k);
        f16x8 v4 = *(const f16x8*)(Xh + (size_t)s4 * DD + k);
        f16x8 v5 = *(const f16x8*)(Xh + (size_t)s5 * DD + k);
        f16x8 v6 = *(const f16x8*)(Xh + (size_t)s6 * DD + k);
        f16x8 v7 = *(const f16x8*)(Xh + (size_t)s7 * DD + k);
        #pragma unroll
        for (int t = 0; t < 8; ++t) {
            a0[t] += (float)v0[t] + (float)v2[t];
            a1[t] += (float)v1[t] + (float)v3[t];
        }
        #pragma unroll
        for (int t = 0; t < 8; ++t) {
            a0[t] += (float)v4[t] + (float)v6[t];
            a1[t] += (float)v5[t] + (float)v7[t];
        }
    }
    for (; j < end; ++j) {
        int s = srcs1[j];
        f16x8 v = *(const f16x8*)(Xh + (size_t)s * DD + k);
        #pragma unroll
        for (int t = 0; t < 8; ++t) a0[t] += (float)v[t];
    }
    float f = degE[e];
    f16x8 ob;
    #pragma unroll
    for (int t = 0; t < 8; ++t) ob[t] = (_Float16)(f * (a0[t] + a1[t]));
    *(f16x8*)(XeH + (size_t)e * DD + k) = ob;
}

// ---------------------------------------------------------------------------
// k_node_gather: Xi[v] = (1-a)*degV[v] * sum XeH[srcs2[j]] + a*X0[v] (-> out)
// XeH is fp16: 8B per lane per row (half-wave covers the 256B row).
// ---------------------------------------------------------------------------
__global__ __launch_bounds__(256)
void k_node_gather(const _Float16* __restrict__ XeH, const int* __restrict__ off,
                   const int* __restrict__ srcs, const float* __restrict__ degV,
                   const float* __restrict__ X0, const float* __restrict__ alphaP,
                   float* __restrict__ Xi, int n_nodes) {
    int gid = blockIdx.x * 256 + threadIdx.x;
    int v = gid >> 5;
    if (v >= n_nodes) return;
    int k = (gid & 31) << 2;
    int beg = off[v], end = off[v + 1];
    float4 acc0 = {0, 0, 0, 0}, acc1 = {0, 0, 0, 0};
    int j = beg;
    for (; j + 4 <= end; j += 4) {
        int s0 = srcs[j + 0];
        int s1 = srcs[j + 1];
        int s2 = srcs[j + 2];
        int s3 = srcs[j + 3];
        f16x4 h0 = *(const f16x4*)(XeH + (size_t)s0 * DD + k);
        f16x4 h1 = *(const f16x4*)(XeH + (size_t)s1 * DD + k);
        f16x4 h2 = *(const f16x4*)(XeH + (size_t)s2 * DD + k);
        f16x4 h3 = *(const f16x4*)(XeH + (size_t)s3 * DD + k);
        acc0.x += (float)h0[0]; acc0.y += (float)h0[1]; acc0.z += (float)h0[2]; acc0.w += (float)h0[3];
        acc1.x += (float)h1[0]; acc1.y += (float)h1[1]; acc1.z += (float)h1[2]; acc1.w += (float)h1[3];
        acc0.x += (float)h2[0]; acc0.y += (float)h2[1]; acc0.z += (float)h2[2]; acc0.w += (float)h2[3];
        acc1.x += (float)h3[0]; acc1.y += (float)h3[1]; acc1.z += (float)h3[2]; acc1.w += (float)h3[3];
    }
    for (; j < end; ++j) {
        int s = srcs[j];
        f16x4 h = *(const f16x4*)(XeH + (size_t)s * DD + k);
        acc0.x += (float)h[0]; acc0.y += (float)h[1]; acc0.z += (float)h[2]; acc0.w += (float)h[3];
    }
    float a = alphaP[0];
    float f = (1.0f - a) * degV[v];
    float4 x0 = *(const float4*)(X0 + (size_t)v * DD + k);
    float4 o;
    o.x = f * (acc0.x + acc1.x) + a * x0.x;
    o.y = f * (acc0.y + acc1.y) + a * x0.y;
    o.z = f * (acc0.z + acc1.z) + a * x0.z;
    o.w = f * (acc0.w + acc1.w) + a * x0.w;
    *(float4*)(Xi + (size_t)v * DD + k) = o;
}

// ---------------------------------------------------------------------------
// k_gemm_mfma: out = Xi @ M'^T in place (xio = Xi = out), fp16 MFMA (same
// rate as bf16, 8x the mantissa). One wave per 16-row strip; B-frags direct
// loads from M' (32 KB, L1-hot); C/D layout col=lane&15, row=quad*4+reg.
// ---------------------------------------------------------------------------
__global__ __launch_bounds__(256)
void k_gemm_mfma(float* xio, const _Float16* __restrict__ Mh, int n_rows) {
    const int lane = threadIdx.x & 63;
    const int wid  = threadIdx.x >> 6;
    const int m16  = lane & 15;
    const int quad = lane >> 4;
    const int kq   = quad * 8;

    const int strip = blockIdx.x * 4 + wid;
    const int row0 = strip * 16;
    if (row0 >= n_rows) return;

    int arow = row0 + m16;
    if (arow >= n_rows) arow = n_rows - 1;       // inert when M%16==0
    const float* xr = xio + (size_t)arow * DD;

    f16x8 af[4];
    #pragma unroll
    for (int kf = 0; kf < 4; ++kf) {
        const float* p = xr + kf * 32 + kq;
        float4 lo = *(const float4*)p;
        float4 hi = *(const float4*)(p + 4);
        f16x8 t;
        t[0] = (_Float16)lo.x; t[1] = (_Float16)lo.y;
        t[2] = (_Float16)lo.z; t[3] = (_Float16)lo.w;
        t[4] = (_Float16)hi.x; t[5] = (_Float16)hi.y;
        t[6] = (_Float16)hi.z; t[7] = (_Float16)hi.w;
        af[kf] = t;
    }

    #pragma unroll
    for (int nt = 0; nt < 8; ++nt) {
        const _Float16* mr = Mh + (size_t)(nt * 16 + m16) * DD + kq;
        f32x4 acc = {0.f, 0.f, 0.f, 0.f};
        #pragma unroll
        for (int kf = 0; kf < 4; ++kf) {
            f16x8 bfrag = *(const f16x8*)(mr + kf * 32);
            acc = __builtin_amdgcn_mfma_f32_16x16x32_f16(af[kf], bfrag, acc, 0, 0, 0);
        }
        const int col = nt * 16 + m16;
        #pragma unroll
        for (int r = 0; r < 4; ++r) {
            int row = row0 + quad * 4 + r;
            if (row < n_rows)
                xio[(size_t)row * DD + col] = acc[r];
        }
    }
}

// ---------------------------------------------------------------------------
extern "C" void kernel_launch(void* const* d_in, const int* in_sizes, int n_in,
                              void* d_out, int out_size, void* d_ws, size_t ws_size,
                              hipStream_t stream) {
    const float* X     = (const float*)d_in[0];
    const float* X0    = (const float*)d_in[1];
    const float* degE  = (const float*)d_in[2];
    const float* degV  = (const float*)d_in[3];
    const float* alpha = (const float*)d_in[4];
    const float* beta  = (const float*)d_in[5];
    const float* W     = (const float*)d_in[6];
    const int*   g1s   = (const int*)d_in[7];
    const int*   g1d   = (const int*)d_in[8];
    const int*   g2s   = (const int*)d_in[9];
    const int*   g2d   = (const int*)d_in[10];
    float* out = (float*)d_out;

    const int n_nodes = in_sizes[3];        // 100000
    const int n_edges = in_sizes[2];        // 20000
    const int nnz     = in_sizes[7];        // 800000
    const int nx      = n_nodes * DD;       // 12.8M elems

    // --- workspace layout (4-byte units) ---
    // XeH (fp16 [E][128], 1.28M words) written by the fused kernel.
    // rank1/rank2 SHARE one slot (rank1 dead after fill1; rank2 written after).
    // cnt1p overlays srcs1 (dead until fill1, after scan1); cnt2p overlays
    // srcs2 exactly (100000*PAD2 == nnz), dead after scan2, before fill2.
    // Xh (fp16 copy of X, 25.6MB) lives in d_out: dead after k_h2_egather,
    // which completes before k_node_gather writes out (stream order).
    int*   wsi   = (int*)d_ws;
    _Float16* XeH = (_Float16*)d_ws;                   // [E*128] fp16 (5.12 MB)
    size_t o     = (size_t)n_edges * DD / 2;           // words
    int*   rank1 = wsi + o;                            // [nnz]
    int*   rank2 = rank1;                              // shared slot
    o += nnz;
    int*   off1  = wsi + o;          o += n_edges + 1;
    int*   off2  = wsi + o;          o += n_nodes + 1;
    size_t srcs_base = o;
    int*   srcs1 = wsi + o;          o += nnz;
    int*   srcs2 = wsi + o;          o += nnz;
    int*   bsum  = wsi + o;          o += 64;
    _Float16* Mh = (_Float16*)(wsi + o); o += DD * DD / 2; // fp16 [128][128]
    int*   cnt1p = wsi + srcs_base;                    // [n_edges*PAD1]
    int*   cnt2p = wsi + srcs_base + nnz;              // [n_nodes*PAD2] == srcs2
    _Float16* Xh = (_Float16*)d_out;                   // fp16 [N][128] scratch

    // zero both padded counter regions (they live inside srcs1/srcs2)
    hipMemsetAsync(cnt1p, 0, 2 * (size_t)nnz * sizeof(int), stream);

    const int nb1 = (n_edges + SCAN_CHUNK - 1) / SCAN_CHUNK;   // 10
    const int nb2 = (n_nodes + SCAN_CHUNK - 1) / SCAN_CHUNK;   // 49
    const int no  = (nnz + 7) / 8;                             // octs per graph
    const int hb  = (no + 255) / 256;                          // hist blocks: 391
    const int cb  = (nx / 8 + 255) / 256;                      // conv blocks: 6250
    const int nq  = (nnz + 3) / 4;                             // quads per graph
    const int qb  = (nq + 255) / 256;                          // fill blocks

    // ---- g1 hist + prep_w + X->fp16, one grid (conv hides under atomics) ----
    k_hist1<<<hb + 8 + cb, 256, 0, stream>>>(g1d, cnt1p, rank1, nnz, no, hb,
                                             W, beta, Mh, X, Xh, nx);
    k_scan_blocks<<<nb1, 256, 0, stream>>>(cnt1p, off1, bsum, n_edges, PAD1);
    k_scan_add<<<(n_edges + 255) / 256, 256, 0, stream>>>(off1, bsum, n_edges, nnz);
    k_fill<<<qb, 256, 0, stream>>>(g1d, g1s, off1, rank1, srcs1, nnz);

    // ---- fused: g2 histogram (no deps) rides under the fp16 edge gather ----
    const int egb = (n_edges * 16 + 255) / 256;                // 1250
    k_h2_egather<<<hb + egb, 256, 0, stream>>>(g2d, cnt2p, rank2, nnz, no, hb,
                                               Xh, off1, srcs1, degE, XeH, n_edges);

    // ---- g2 CSR finalize ----
    k_scan_blocks<<<nb2, 256, 0, stream>>>(cnt2p, off2, bsum, n_nodes, PAD2);
    k_scan_add<<<(n_nodes + 255) / 256, 256, 0, stream>>>(off2, bsum, n_nodes, nnz);
    k_fill<<<qb, 256, 0, stream>>>(g2d, g2s, off2, rank2, srcs2, nnz);

    // ---- node gather (reads fp16 Xe; writes out -> Xh is dead by now) ----
    k_node_gather<<<(n_nodes * 32 + 255) / 256, 256, 0, stream>>>(
        XeH, off2, srcs2, degV, X0, alpha, out, n_nodes);

    // ---- out = Xi @ M'^T, in place, fp16 MFMA ----
    const int nstrips = (n_nodes + 15) / 16;           // 6250
    k_gemm_mfma<<<(nstrips + 3) / 4, 256, 0, stream>>>(out, Mh, n_nodes);
}

// Round 4
// 354.640 us; speedup vs baseline: 1.1642x; 1.0568x over previous
//
#include <hip/hip_runtime.h>

#define DD 128
#define SCAN_CHUNK 2048   // 256 threads x 8 elements per scan block
#define PAD1 16           // cnt1 stride: one counter per 64B line
#define PAD2 8            // cnt2 stride: two counters per 64B line

typedef __attribute__((ext_vector_type(8))) _Float16 f16x8;
typedef __attribute__((ext_vector_type(4))) _Float16 f16x4;
typedef __attribute__((ext_vector_type(4))) float f32x4;

// ---------------------------------------------------------------------------
// k_hist1: three block ranges, all independent:
//   [0, hb)        : histogram g1 into padded counters, capture ranks
//   [hb, hb+8)     : fold (1-b)I + b*W into fp16 M' (prep_w)
//   [hb+8, +cb)    : convert X (fp32) -> Xh (fp16) for the cheap gather
// ---------------------------------------------------------------------------
__global__ __launch_bounds__(256)
void k_hist1(const int* __restrict__ g1d, int* __restrict__ cnt1p,
             int* __restrict__ rank1, int nnz, int no, int hb,
             const float* __restrict__ W, const float* __restrict__ betaP,
             _Float16* __restrict__ Mh,
             const float* __restrict__ X, _Float16* __restrict__ Xh, int nx) {
    const int b = blockIdx.x;
    if (b < hb) {                              // ---- hist g1 ----
        int q = b * 256 + threadIdx.x;
        if (q >= no) return;
        int i = q << 3;
        if (i + 8 <= nnz) {
            int4 d0 = *(const int4*)(g1d + i);
            int4 d1 = *(const int4*)(g1d + i + 4);
            int r0 = atomicAdd(&cnt1p[d0.x * PAD1], 1);
            int r1 = atomicAdd(&cnt1p[d0.y * PAD1], 1);
            int r2 = atomicAdd(&cnt1p[d0.z * PAD1], 1);
            int r3 = atomicAdd(&cnt1p[d0.w * PAD1], 1);
            int r4 = atomicAdd(&cnt1p[d1.x * PAD1], 1);
            int r5 = atomicAdd(&cnt1p[d1.y * PAD1], 1);
            int r6 = atomicAdd(&cnt1p[d1.z * PAD1], 1);
            int r7 = atomicAdd(&cnt1p[d1.w * PAD1], 1);
            *(int4*)(rank1 + i)     = make_int4(r0, r1, r2, r3);
            *(int4*)(rank1 + i + 4) = make_int4(r4, r5, r6, r7);
        } else {
            for (; i < nnz; ++i) rank1[i] = atomicAdd(&cnt1p[g1d[i] * PAD1], 1);
        }
        return;
    }
    if (b < hb + 8) {                          // ---- prep_w (fp16 M') ----
        int gid = (b - hb) * 256 + threadIdx.x;     // 2048 threads, 8 elems each
        if (gid >= DD * DD / 8) return;
        int c  = gid >> 4;
        int k0 = (gid & 15) << 3;
        float bb = betaP[0], ib = 1.0f - bb;
        const float* p = W + c * DD + k0;
        float4 lo = *(const float4*)p, hi = *(const float4*)(p + 4);
        float v[8] = {lo.x, lo.y, lo.z, lo.w, hi.x, hi.y, hi.z, hi.w};
        f16x8 t;
        #pragma unroll
        for (int j = 0; j < 8; ++j) {
            float m = bb * v[j] + ((k0 + j) == c ? ib : 0.0f);
            t[j] = (_Float16)m;
        }
        *(f16x8*)(Mh + (size_t)c * DD + k0) = t;
        return;
    }
    // ---- X -> fp16 conversion ----
    int gid = (b - hb - 8) * 256 + threadIdx.x;
    int i = gid << 3;
    if (i + 8 <= nx) {
        float4 lo = *(const float4*)(X + i);
        float4 hi = *(const float4*)(X + i + 4);
        f16x8 t;
        t[0] = (_Float16)lo.x; t[1] = (_Float16)lo.y;
        t[2] = (_Float16)lo.z; t[3] = (_Float16)lo.w;
        t[4] = (_Float16)hi.x; t[5] = (_Float16)hi.y;
        t[6] = (_Float16)hi.z; t[7] = (_Float16)hi.w;
        *(f16x8*)(Xh + i) = t;
    } else {
        for (; i < nx; ++i) Xh[i] = (_Float16)X[i];
    }
}

// ---------------------------------------------------------------------------
// k_scan_blocks: chunk-local EXCLUSIVE scan of padded counters -> off[]
// (chunk-local values only; consumers add the chunk base from bsum),
// per-chunk totals -> bsum[b]. Stores off[idx] for idx <= n so off[n] exists.
// ---------------------------------------------------------------------------
__global__ __launch_bounds__(256)
void k_scan_blocks(const int* __restrict__ cnt, int* __restrict__ off,
                   int* __restrict__ bsum, int n, int str) {
    __shared__ int sh[256];
    const int tid = threadIdx.x;
    const int base = blockIdx.x * SCAN_CHUNK + tid * 8;
    int v[8];
    int s = 0;
    #pragma unroll
    for (int j = 0; j < 8; ++j) {
        int idx = base + j;
        v[j] = (idx < n) ? cnt[(size_t)idx * str] : 0;
        s += v[j];
    }
    sh[tid] = s;
    __syncthreads();
    for (int d = 1; d < 256; d <<= 1) {
        int y = (tid >= d) ? sh[tid - d] : 0;
        __syncthreads();
        sh[tid] += y;
        __syncthreads();
    }
    int incl = sh[tid];
    int run = incl - s;
    #pragma unroll
    for (int j = 0; j < 8; ++j) {
        int idx = base + j;
        if (idx <= n) off[idx] = run;
        run += v[j];
    }
    if (tid == 255) bsum[blockIdx.x] = incl;      // chunk total (inclusive)
}

// ---------------------------------------------------------------------------
// k_fill: srcs[off[d] + pref[d>>11] + rank[i]] = src[i]. Chunk prefix of
// bsum computed once per block in LDS (nb <= 49). No atomics.
// ---------------------------------------------------------------------------
__global__ __launch_bounds__(256)
void k_fill(const int* __restrict__ dst, const int* __restrict__ src,
            const int* __restrict__ off, const int* __restrict__ rank,
            const int* __restrict__ bsum, int nb,
            int* __restrict__ out, int nnz) {
    __shared__ int pref[64];
    if (threadIdx.x == 0) {
        int run = 0;
        for (int i = 0; i < nb; ++i) { pref[i] = run; run += bsum[i]; }
        pref[nb] = run;
    }
    __syncthreads();
    int q = blockIdx.x * 256 + threadIdx.x;
    int i = q << 2;
    if (i + 4 <= nnz) {
        int4 d = *(const int4*)(dst + i);
        int4 s = *(const int4*)(src + i);
        int4 r = *(const int4*)(rank + i);
        int o0 = off[d.x] + pref[d.x >> 11];
        int o1 = off[d.y] + pref[d.y >> 11];
        int o2 = off[d.z] + pref[d.z >> 11];
        int o3 = off[d.w] + pref[d.w >> 11];
        out[o0 + r.x] = s.x;
        out[o1 + r.y] = s.y;
        out[o2 + r.z] = s.z;
        out[o3 + r.w] = s.w;
    } else {
        for (; i < nnz; ++i)
            out[off[dst[i]] + pref[dst[i] >> 11] + rank[i]] = src[i];
    }
}

// ---------------------------------------------------------------------------
// k_h2_egather: fused kernel.
//   blocks [0,H):  histogram g2 (atomic/latency-bound, no upstream deps)
//   blocks [H,..): edge gather, ONE WAVE PER EDGE: lanes = 4 refs x 16
//                  column-groups -> 4-8 rows in flight per wave; final
//                  shfl_xor(16/32) reduce; group 0 writes the fp16 row.
// ---------------------------------------------------------------------------
__global__ __launch_bounds__(256)
void k_h2_egather(const int* __restrict__ g2d, int* __restrict__ cnt2p,
                  int* __restrict__ rank2, int nnz, int no, int H,
                  const _Float16* __restrict__ Xh, const int* __restrict__ off1,
                  const int* __restrict__ bsum1, int nb1,
                  const int* __restrict__ srcs1, const float* __restrict__ degE,
                  _Float16* __restrict__ XeH, int n_edges) {
    if (blockIdx.x < H) {                         // ---- hist g2 path ----
        int q = blockIdx.x * 256 + threadIdx.x;
        if (q >= no) return;
        int i = q << 3;
        if (i + 8 <= nnz) {
            int4 d0 = *(const int4*)(g2d + i);
            int4 d1 = *(const int4*)(g2d + i + 4);
            int r0 = atomicAdd(&cnt2p[d0.x * PAD2], 1);
            int r1 = atomicAdd(&cnt2p[d0.y * PAD2], 1);
            int r2 = atomicAdd(&cnt2p[d0.z * PAD2], 1);
            int r3 = atomicAdd(&cnt2p[d0.w * PAD2], 1);
            int r4 = atomicAdd(&cnt2p[d1.x * PAD2], 1);
            int r5 = atomicAdd(&cnt2p[d1.y * PAD2], 1);
            int r6 = atomicAdd(&cnt2p[d1.z * PAD2], 1);
            int r7 = atomicAdd(&cnt2p[d1.w * PAD2], 1);
            *(int4*)(rank2 + i)     = make_int4(r0, r1, r2, r3);
            *(int4*)(rank2 + i + 4) = make_int4(r4, r5, r6, r7);
        } else {
            for (; i < nnz; ++i) rank2[i] = atomicAdd(&cnt2p[g2d[i] * PAD2], 1);
        }
        return;
    }
    // ---- edge gather path: one wave per edge ----
    __shared__ int pref[16];
    if (threadIdx.x == 0) {
        int run = 0;
        for (int i = 0; i < nb1; ++i) { pref[i] = run; run += bsum1[i]; }
        pref[nb1] = run;
    }
    __syncthreads();
    const int wid  = threadIdx.x >> 6;
    const int lane = threadIdx.x & 63;
    int e = (blockIdx.x - H) * 4 + wid;
    if (e >= n_edges) return;
    const int g = lane >> 4;                      // ref slot 0..3
    const int c = lane & 15;                      // column group (cols c*8..c*8+7)
    int beg = off1[e] + pref[e >> 11];
    int end = off1[e + 1] + pref[(e + 1) >> 11];
    float a0[8] = {0, 0, 0, 0, 0, 0, 0, 0};
    float a1[8] = {0, 0, 0, 0, 0, 0, 0, 0};
    int j = beg + g;
    for (; j + 4 < end; j += 8) {                 // two refs per group per iter
        int s0 = srcs1[j];
        int s1 = srcs1[j + 4];
        f16x8 v0 = *(const f16x8*)(Xh + (size_t)s0 * DD + c * 8);
        f16x8 v1 = *(const f16x8*)(Xh + (size_t)s1 * DD + c * 8);
        #pragma unroll
        for (int t = 0; t < 8; ++t) { a0[t] += (float)v0[t]; a1[t] += (float)v1[t]; }
    }
    if (j < end) {
        int s = srcs1[j];
        f16x8 v = *(const f16x8*)(Xh + (size_t)s * DD + c * 8);
        #pragma unroll
        for (int t = 0; t < 8; ++t) a0[t] += (float)v[t];
    }
    float r[8];
    #pragma unroll
    for (int t = 0; t < 8; ++t) r[t] = a0[t] + a1[t];
    #pragma unroll
    for (int t = 0; t < 8; ++t) r[t] += __shfl_xor(r[t], 16);
    #pragma unroll
    for (int t = 0; t < 8; ++t) r[t] += __shfl_xor(r[t], 32);
    if (g == 0) {
        float f = degE[e];
        f16x8 ob;
        #pragma unroll
        for (int t = 0; t < 8; ++t) ob[t] = (_Float16)(f * r[t]);
        *(f16x8*)(XeH + (size_t)e * DD + c * 8) = ob;
    }
}

// ---------------------------------------------------------------------------
// k_ng_gemm: fused node gather + GCNII blend + GEMM.
// Block = 4 waves; wave owns a 16-row strip. Phase 1: 64 lanes = 16 nodes x
// 4 col-quarters gather sum XeH[srcs2[j]], blend (1-a)*degV*acc + a*X0,
// convert fp16, write to XOR-swizzled LDS. Phase 2: same wave runs the
// 16-strip MFMA against M' (global, L1-hot) and stores out directly.
// Removes the 102 MB Xi global round-trip of the split version.
// ---------------------------------------------------------------------------
__global__ __launch_bounds__(256)
void k_ng_gemm(const _Float16* __restrict__ XeH, const int* __restrict__ off2,
               const int* __restrict__ bsum2, int nb2,
               const int* __restrict__ srcs2, const float* __restrict__ degV,
               const float* __restrict__ X0, const float* __restrict__ alphaP,
               const _Float16* __restrict__ Mh, float* __restrict__ out,
               int n_nodes) {
    __shared__ int pref[64];
    __shared__ _Float16 xi_lds[4][16 * DD];       // 4 waves x 4KB
    const int tid = threadIdx.x;
    if (tid == 0) {
        int run = 0;
        for (int i = 0; i < nb2; ++i) { pref[i] = run; run += bsum2[i]; }
        pref[nb2] = run;
    }
    __syncthreads();
    const int wid  = tid >> 6;
    const int lane = tid & 63;
    const int strip = blockIdx.x * 4 + wid;
    const int row0 = strip * 16;
    const bool live = row0 < n_nodes;
    _Float16* lbase = &xi_lds[wid][0];

    // ---- phase 1: gather 16 rows into swizzled LDS ----
    const int r16 = lane >> 2;                    // node within strip
    const int sl  = lane & 3;                     // col quarter (32 cols)
    const int row = row0 + r16;
    if (live) {
        float acc[32];
        #pragma unroll
        for (int t = 0; t < 32; ++t) acc[t] = 0.0f;
        if (row < n_nodes) {
            int beg = off2[row] + pref[row >> 11];
            int end = off2[row + 1] + pref[(row + 1) >> 11];
            int j = beg;
            for (; j + 2 <= end; j += 2) {
                int s0 = srcs2[j];
                int s1 = srcs2[j + 1];
                const _Float16* p0 = XeH + (size_t)s0 * DD + sl * 32;
                const _Float16* p1 = XeH + (size_t)s1 * DD + sl * 32;
                f16x8 u0 = *(const f16x8*)(p0);
                f16x8 u1 = *(const f16x8*)(p0 + 8);
                f16x8 u2 = *(const f16x8*)(p0 + 16);
                f16x8 u3 = *(const f16x8*)(p0 + 24);
                f16x8 w0 = *(const f16x8*)(p1);
                f16x8 w1 = *(const f16x8*)(p1 + 8);
                f16x8 w2 = *(const f16x8*)(p1 + 16);
                f16x8 w3 = *(const f16x8*)(p1 + 24);
                #pragma unroll
                for (int t = 0; t < 8; ++t) {
                    acc[t]      += (float)u0[t] + (float)w0[t];
                    acc[8 + t]  += (float)u1[t] + (float)w1[t];
                    acc[16 + t] += (float)u2[t] + (float)w2[t];
                    acc[24 + t] += (float)u3[t] + (float)w3[t];
                }
            }
            if (j < end) {
                int s = srcs2[j];
                const _Float16* p0 = XeH + (size_t)s * DD + sl * 32;
                f16x8 u0 = *(const f16x8*)(p0);
                f16x8 u1 = *(const f16x8*)(p0 + 8);
                f16x8 u2 = *(const f16x8*)(p0 + 16);
                f16x8 u3 = *(const f16x8*)(p0 + 24);
                #pragma unroll
                for (int t = 0; t < 8; ++t) {
                    acc[t]      += (float)u0[t];
                    acc[8 + t]  += (float)u1[t];
                    acc[16 + t] += (float)u2[t];
                    acc[24 + t] += (float)u3[t];
                }
            }
            float a = alphaP[0];
            float f = (1.0f - a) * degV[row];
            const float* x0p = X0 + (size_t)row * DD + sl * 32;
            #pragma unroll
            for (int c2 = 0; c2 < 4; ++c2) {
                float4 xa = *(const float4*)(x0p + c2 * 8);
                float4 xb = *(const float4*)(x0p + c2 * 8 + 4);
                f16x8 h;
                h[0] = (_Float16)(f * acc[c2 * 8 + 0] + a * xa.x);
                h[1] = (_Float16)(f * acc[c2 * 8 + 1] + a * xa.y);
                h[2] = (_Float16)(f * acc[c2 * 8 + 2] + a * xa.z);
                h[3] = (_Float16)(f * acc[c2 * 8 + 3] + a * xa.w);
                h[4] = (_Float16)(f * acc[c2 * 8 + 4] + a * xb.x);
                h[5] = (_Float16)(f * acc[c2 * 8 + 5] + a * xb.y);
                h[6] = (_Float16)(f * acc[c2 * 8 + 6] + a * xb.z);
                h[7] = (_Float16)(f * acc[c2 * 8 + 7] + a * xb.w);
                int byte = r16 * 256 + sl * 64 + c2 * 16;
                byte ^= (r16 & 7) << 4;            // bank swizzle
                *(f16x8*)((char*)lbase + byte) = h;
            }
        } else {
            // dead row inside live strip: zero its LDS slots
            f16x8 z = {0, 0, 0, 0, 0, 0, 0, 0};
            #pragma unroll
            for (int c2 = 0; c2 < 4; ++c2) {
                int byte = r16 * 256 + sl * 64 + c2 * 16;
                byte ^= (r16 & 7) << 4;
                *(f16x8*)((char*)lbase + byte) = z;
            }
        }
    }
    __syncthreads();
    if (!live) return;

    // ---- phase 2: MFMA strip-GEMM, A from swizzled LDS, B from M' ----
    const int m16  = lane & 15;
    const int quad = lane >> 4;
    const int kq   = quad * 8;
    f16x8 af[4];
    #pragma unroll
    for (int kf = 0; kf < 4; ++kf) {
        int byte = m16 * 256 + kf * 64 + quad * 16;
        byte ^= (m16 & 7) << 4;
        af[kf] = *(const f16x8*)((const char*)lbase + byte);
    }
    #pragma unroll
    for (int nt = 0; nt < 8; ++nt) {
        const _Float16* mr = Mh + (size_t)(nt * 16 + m16) * DD + kq;
        f32x4 acc = {0.f, 0.f, 0.f, 0.f};
        #pragma unroll
        for (int kf = 0; kf < 4; ++kf) {
            f16x8 bfrag = *(const f16x8*)(mr + kf * 32);
            acc = __builtin_amdgcn_mfma_f32_16x16x32_f16(af[kf], bfrag, acc, 0, 0, 0);
        }
        const int col = nt * 16 + m16;
        #pragma unroll
        for (int r = 0; r < 4; ++r) {
            int orow = row0 + quad * 4 + r;
            if (orow < n_nodes)
                out[(size_t)orow * DD + col] = acc[r];
        }
    }
}

// ---------------------------------------------------------------------------
extern "C" void kernel_launch(void* const* d_in, const int* in_sizes, int n_in,
                              void* d_out, int out_size, void* d_ws, size_t ws_size,
                              hipStream_t stream) {
    const float* X     = (const float*)d_in[0];
    const float* X0    = (const float*)d_in[1];
    const float* degE  = (const float*)d_in[2];
    const float* degV  = (const float*)d_in[3];
    const float* alpha = (const float*)d_in[4];
    const float* beta  = (const float*)d_in[5];
    const float* W     = (const float*)d_in[6];
    const int*   g1s   = (const int*)d_in[7];
    const int*   g1d   = (const int*)d_in[8];
    const int*   g2s   = (const int*)d_in[9];
    const int*   g2d   = (const int*)d_in[10];
    float* out = (float*)d_out;

    const int n_nodes = in_sizes[3];        // 100000
    const int n_edges = in_sizes[2];        // 20000
    const int nnz     = in_sizes[7];        // 800000
    const int nx      = n_nodes * DD;       // 12.8M elems

    // --- workspace layout (4-byte units) ---
    // XeH (fp16 [E][128]) first; rank1/rank2 share one slot; cnt1p overlays
    // srcs1; cnt2p overlays srcs2 exactly (n_nodes*PAD2 == nnz).
    // Xh (fp16 copy of X) lives in d_out: dead after k_h2_egather, which
    // completes before k_ng_gemm writes out (stream order).
    int*   wsi   = (int*)d_ws;
    _Float16* XeH = (_Float16*)d_ws;                   // [E*128] fp16 (5.12 MB)
    size_t o     = (size_t)n_edges * DD / 2;           // words
    int*   rank1 = wsi + o;                            // [nnz]
    int*   rank2 = rank1;                              // shared slot
    o += nnz;
    int*   off1  = wsi + o;          o += n_edges + 1;
    int*   off2  = wsi + o;          o += n_nodes + 1;
    size_t srcs_base = o;
    int*   srcs1 = wsi + o;          o += nnz;
    int*   srcs2 = wsi + o;          o += nnz;
    int*   bsum  = wsi + o;          o += 128;
    _Float16* Mh = (_Float16*)(wsi + o); o += DD * DD / 2; // fp16 [128][128]
    int*   cnt1p = wsi + srcs_base;                    // [n_edges*PAD1]
    int*   cnt2p = wsi + srcs_base + nnz;              // [n_nodes*PAD2] == srcs2
    _Float16* Xh = (_Float16*)d_out;                   // fp16 [N][128] scratch

    // zero both padded counter regions (they live inside srcs1/srcs2)
    hipMemsetAsync(cnt1p, 0, 2 * (size_t)nnz * sizeof(int), stream);

    const int nb1 = (n_edges + SCAN_CHUNK - 1) / SCAN_CHUNK;   // 10
    const int nb2 = (n_nodes + SCAN_CHUNK - 1) / SCAN_CHUNK;   // 49
    const int no  = (nnz + 7) / 8;                             // octs per graph
    const int hb  = (no + 255) / 256;                          // hist blocks: 391
    const int cb  = (nx / 8 + 255) / 256;                      // conv blocks: 6250
    const int nq  = (nnz + 3) / 4;                             // quads per graph
    const int qb  = (nq + 255) / 256;                          // fill blocks

    // ---- g1 hist + prep_w + X->fp16, one grid ----
    k_hist1<<<hb + 8 + cb, 256, 0, stream>>>(g1d, cnt1p, rank1, nnz, no, hb,
                                             W, beta, Mh, X, Xh, nx);
    k_scan_blocks<<<nb1, 256, 0, stream>>>(cnt1p, off1, bsum, n_edges, PAD1);
    k_fill<<<qb, 256, 0, stream>>>(g1d, g1s, off1, rank1, bsum, nb1, srcs1, nnz);

    // ---- fused: g2 histogram rides under the wave-per-edge fp16 gather ----
    const int egb = (n_edges + 3) / 4;                         // 5000
    k_h2_egather<<<hb + egb, 256, 0, stream>>>(g2d, cnt2p, rank2, nnz, no, hb,
                                               Xh, off1, bsum, nb1,
                                               srcs1, degE, XeH, n_edges);

    // ---- g2 CSR finalize ----
    k_scan_blocks<<<nb2, 256, 0, stream>>>(cnt2p, off2, bsum + 64, n_nodes, PAD2);
    k_fill<<<qb, 256, 0, stream>>>(g2d, g2s, off2, rank2, bsum + 64, nb2, srcs2, nnz);

    // ---- fused node gather + blend + MFMA GEMM -> out ----
    const int nstrips = (n_nodes + 15) / 16;                   // 6250
    k_ng_gemm<<<(nstrips + 3) / 4, 256, 0, stream>>>(
        XeH, off2, bsum + 64, nb2, srcs2, degV, X0, alpha, Mh, out, n_nodes);
}